// Round 1
// baseline (644.099 us; speedup 1.0000x reference)
//
#include <hip/hip_runtime.h>
#include <hip/hip_fp16.h>

#define N_ROWS 8192
#define K_DIM  4096
#define M_DIM  4096

typedef __attribute__((ext_vector_type(8))) _Float16 half8;
typedef __attribute__((ext_vector_type(4))) _Float16 half4v;
typedef __attribute__((ext_vector_type(4))) float    f32x4;

// ---------------------------------------------------------------------------
// Kernel 1: per-row amax -> softplus scale -> int16 fake-quant -> f16
// One block (256 threads) per row of x [N, K]. Each thread holds 16 floats.
// ---------------------------------------------------------------------------
__global__ __launch_bounds__(256) void quant_kernel(
    const float* __restrict__ x, _Float16* __restrict__ xq, float* __restrict__ sx)
{
    const int row = blockIdx.x;
    const int t   = threadIdx.x;
    const float4* xr4 = (const float4*)(x + (size_t)row * K_DIM);

    float4 v[4];
    float am = 0.0f;
#pragma unroll
    for (int i = 0; i < 4; ++i) {
        v[i] = xr4[i * 256 + t];
        am = fmaxf(am, fmaxf(fmaxf(fabsf(v[i].x), fabsf(v[i].y)),
                             fmaxf(fabsf(v[i].z), fabsf(v[i].w))));
    }
    // wave (64-lane) reduction
#pragma unroll
    for (int off = 32; off; off >>= 1)
        am = fmaxf(am, __shfl_xor(am, off, 64));
    __shared__ float red[4];
    if ((t & 63) == 0) red[t >> 6] = am;
    __syncthreads();
    am = fmaxf(fmaxf(red[0], red[1]), fmaxf(red[2], red[3]));

    const float sp    = (am > 20.0f) ? am : log1pf(expf(am));  // softplus
    const float scale = sp / 32767.0f;
    const float inv   = 32767.0f / sp;
    if (t == 0) sx[row] = scale;

    half4v* out4 = (half4v*)(xq + (size_t)row * K_DIM);
#pragma unroll
    for (int i = 0; i < 4; ++i) {
        float q0 = fminf(fmaxf(rintf(v[i].x * inv), -32768.0f), 32767.0f);
        float q1 = fminf(fmaxf(rintf(v[i].y * inv), -32768.0f), 32767.0f);
        float q2 = fminf(fmaxf(rintf(v[i].z * inv), -32768.0f), 32767.0f);
        float q3 = fminf(fmaxf(rintf(v[i].w * inv), -32768.0f), 32767.0f);
        half4v h;
        h[0] = (_Float16)q0; h[1] = (_Float16)q1;
        h[2] = (_Float16)q2; h[3] = (_Float16)q3;
        out4[i * 256 + t] = h;
    }
}

// ---------------------------------------------------------------------------
// Kernel 2: fold dual-int8 planes into one fp16 weight: W' = s0*w0 + s1*w1
// Each thread: 8 consecutive elements of one row o.
// ---------------------------------------------------------------------------
__global__ __launch_bounds__(256) void fold_kernel(
    const float* __restrict__ w0, const float* __restrict__ w1,
    const float* __restrict__ s0, const float* __restrict__ s1,
    _Float16* __restrict__ wp)
{
    const size_t gid  = (size_t)blockIdx.x * 256 + threadIdx.x;
    const size_t base = gid * 8;
    const int    o    = (int)(base >> 12);   // /4096, all 8 elems in same row
    const float  a = s0[o], b = s1[o];

    const float4* p0 = (const float4*)(w0 + base);
    const float4* p1 = (const float4*)(w1 + base);
    float4 u0 = p0[0], u1 = p0[1];
    float4 v0 = p1[0], v1 = p1[1];

    half8 h;
    h[0] = (_Float16)(a * u0.x + b * v0.x);
    h[1] = (_Float16)(a * u0.y + b * v0.y);
    h[2] = (_Float16)(a * u0.z + b * v0.z);
    h[3] = (_Float16)(a * u0.w + b * v0.w);
    h[4] = (_Float16)(a * u1.x + b * v1.x);
    h[5] = (_Float16)(a * u1.y + b * v1.y);
    h[6] = (_Float16)(a * u1.z + b * v1.z);
    h[7] = (_Float16)(a * u1.w + b * v1.w);
    *(half8*)(wp + base) = h;
}

// ---------------------------------------------------------------------------
// Kernel 3: NT GEMM  out[n,o] = (sum_k Xq[n,k]*Wp[o,k]) * sx[n] + bias[o]
// m97 structure: 128x128 block tile, BK=32, 4 waves (2x2), each wave 64x64
// via 4x4 grid of 16x16x32 f16 MFMA. global_load_lds width=16 staging.
// ---------------------------------------------------------------------------
__device__ inline void async_load16(const void* g, void* l)
{
    __builtin_amdgcn_global_load_lds(
        (const __attribute__((address_space(1))) void*)g,
        (__attribute__((address_space(3))) void*)l, 16, 0, 0);
}

__global__ __launch_bounds__(256) void gemm_kernel(
    const _Float16* __restrict__ A,   // [N, K]  quantized activations
    const _Float16* __restrict__ B,   // [M, K]  folded weights
    const float* __restrict__ sx,     // [N]
    const float* __restrict__ bias,   // [M]
    float* __restrict__ out)          // [N, M]
{
    __shared__ __align__(16) _Float16 As[128 * 32];
    __shared__ __align__(16) _Float16 Bs[128 * 32];

    const int t    = threadIdx.x;
    const int wave = t >> 6;
    const int lane = t & 63;
    const int n0   = blockIdx.y * 128;
    const int o0   = blockIdx.x * 128;

    // staging: wave covers 16 rows/instr, lane -> (row = lane/4, col8 = (lane&3)*8)
    const int srow = lane >> 2;
    const int scol = (lane & 3) * 8;

    // wave's 64x64 subtile position inside the 128x128 block
    const int n_off = (wave >> 1) * 64;
    const int o_off = (wave & 1) * 64;

    // fragment addressing: lane -> (row = lane&15, kchunk = (lane>>4)*8)
    const int fr = lane & 15;
    const int fk = (lane >> 4) * 8;

    f32x4 acc[4][4] = {};

    for (int kk = 0; kk < K_DIM; kk += 32) {
#pragma unroll
        for (int j = 0; j < 2; ++j) {
            const int row = j * 64 + wave * 16 + srow;
            async_load16(A + (size_t)(n0 + row) * K_DIM + kk + scol,
                         &As[row * 32 + scol]);
            async_load16(B + (size_t)(o0 + row) * K_DIM + kk + scol,
                         &Bs[row * 32 + scol]);
        }
        __syncthreads();   // drains vmcnt(0): staged tiles visible

        half8 af[4], bf[4];
#pragma unroll
        for (int i = 0; i < 4; ++i)
            af[i] = *(const half8*)&As[(n_off + i * 16 + fr) * 32 + fk];
#pragma unroll
        for (int j = 0; j < 4; ++j)
            bf[j] = *(const half8*)&Bs[(o_off + j * 16 + fr) * 32 + fk];

#pragma unroll
        for (int i = 0; i < 4; ++i)
#pragma unroll
            for (int j = 0; j < 4; ++j)
                acc[i][j] = __builtin_amdgcn_mfma_f32_16x16x32_f16(
                    af[i], bf[j], acc[i][j], 0, 0, 0);

        __syncthreads();   // tiles consumed before next-iter overwrite
    }

    // epilogue: C/D layout col = lane&15, row = (lane>>4)*4 + reg
#pragma unroll
    for (int i = 0; i < 4; ++i) {
        const int nbase = n0 + n_off + i * 16 + (lane >> 4) * 4;
#pragma unroll
        for (int r = 0; r < 4; ++r) {
            const float s = sx[nbase + r];
            float* orow = out + (size_t)(nbase + r) * M_DIM;
#pragma unroll
            for (int j = 0; j < 4; ++j) {
                const int o = o0 + o_off + j * 16 + (lane & 15);
                orow[o] = acc[i][j][r] * s + bias[o];
            }
        }
    }
}

// ---------------------------------------------------------------------------
extern "C" void kernel_launch(void* const* d_in, const int* in_sizes, int n_in,
                              void* d_out, int out_size, void* d_ws, size_t ws_size,
                              hipStream_t stream)
{
    const float* x    = (const float*)d_in[0];
    const float* w0   = (const float*)d_in[1];
    const float* w1   = (const float*)d_in[2];
    const float* s0   = (const float*)d_in[3];
    const float* s1   = (const float*)d_in[4];
    const float* bias = (const float*)d_in[5];
    float* out = (float*)d_out;

    // workspace layout
    char* ws = (char*)d_ws;
    _Float16* xq = (_Float16*)ws;                                   // 67108864 B
    _Float16* wp = (_Float16*)(ws + (size_t)N_ROWS * K_DIM * 2);    // 33554432 B
    float*    sx = (float*)(ws + (size_t)N_ROWS * K_DIM * 2
                               + (size_t)M_DIM * K_DIM * 2);        // 32768 B

    quant_kernel<<<N_ROWS, 256, 0, stream>>>(x, xq, sx);
    fold_kernel<<<(M_DIM * (size_t)K_DIM) / (256 * 8), 256, 0, stream>>>(w0, w1, s0, s1, wp);

    dim3 grid(M_DIM / 128, N_ROWS / 128);
    gemm_kernel<<<grid, 256, 0, stream>>>(xq, wp, sx, bias, out);
}

// Round 2
// 638.048 us; speedup vs baseline: 1.0095x; 1.0095x over previous
//
#include <hip/hip_runtime.h>
#include <hip/hip_fp16.h>

#define N_ROWS 8192
#define K_DIM  4096
#define M_DIM  4096

typedef __attribute__((ext_vector_type(8))) _Float16 half8;
typedef __attribute__((ext_vector_type(4))) _Float16 half4v;
typedef __attribute__((ext_vector_type(4))) float    f32x4;

// ---------------------------------------------------------------------------
// Fused prologue.
// Blocks [0, 8192):   per-row amax -> softplus scale -> int16 fake-quant -> f16
// Blocks [8192,16384): fold dual-int8 planes: W' = s0*w0 + s1*w1 -> f16
// ---------------------------------------------------------------------------
__global__ __launch_bounds__(256) void prologue_kernel(
    const float* __restrict__ x,  _Float16* __restrict__ xq, float* __restrict__ sx,
    const float* __restrict__ w0, const float* __restrict__ w1,
    const float* __restrict__ s0, const float* __restrict__ s1,
    _Float16* __restrict__ wp)
{
    const int t = threadIdx.x;
    if (blockIdx.x < N_ROWS) {
        // ----- quant path -----
        const int row = blockIdx.x;
        const float4* xr4 = (const float4*)(x + (size_t)row * K_DIM);

        float4 v[4];
        float am = 0.0f;
#pragma unroll
        for (int i = 0; i < 4; ++i) {
            v[i] = xr4[i * 256 + t];
            am = fmaxf(am, fmaxf(fmaxf(fabsf(v[i].x), fabsf(v[i].y)),
                                 fmaxf(fabsf(v[i].z), fabsf(v[i].w))));
        }
#pragma unroll
        for (int off = 32; off; off >>= 1)
            am = fmaxf(am, __shfl_xor(am, off, 64));
        __shared__ float red[4];
        if ((t & 63) == 0) red[t >> 6] = am;
        __syncthreads();
        am = fmaxf(fmaxf(red[0], red[1]), fmaxf(red[2], red[3]));

        const float sp    = (am > 20.0f) ? am : log1pf(expf(am));  // softplus
        const float scale = sp / 32767.0f;
        const float inv   = 32767.0f / sp;
        if (t == 0) sx[row] = scale;

        half4v* out4 = (half4v*)(xq + (size_t)row * K_DIM);
#pragma unroll
        for (int i = 0; i < 4; ++i) {
            float q0 = fminf(fmaxf(rintf(v[i].x * inv), -32768.0f), 32767.0f);
            float q1 = fminf(fmaxf(rintf(v[i].y * inv), -32768.0f), 32767.0f);
            float q2 = fminf(fmaxf(rintf(v[i].z * inv), -32768.0f), 32767.0f);
            float q3 = fminf(fmaxf(rintf(v[i].w * inv), -32768.0f), 32767.0f);
            half4v h;
            h[0] = (_Float16)q0; h[1] = (_Float16)q1;
            h[2] = (_Float16)q2; h[3] = (_Float16)q3;
            out4[i * 256 + t] = h;
        }
    } else {
        // ----- weight-fold path -----
        const size_t gid  = (size_t)(blockIdx.x - N_ROWS) * 256 + t;
        const size_t base = gid * 8;
        const int    o    = (int)(base >> 12);   // /4096: all 8 elems same row
        const float  a = s0[o], b = s1[o];

        const float4* p0 = (const float4*)(w0 + base);
        const float4* p1 = (const float4*)(w1 + base);
        float4 u0 = p0[0], u1 = p0[1];
        float4 v0 = p1[0], v1 = p1[1];

        half8 h;
        h[0] = (_Float16)(a * u0.x + b * v0.x);
        h[1] = (_Float16)(a * u0.y + b * v0.y);
        h[2] = (_Float16)(a * u0.z + b * v0.z);
        h[3] = (_Float16)(a * u0.w + b * v0.w);
        h[4] = (_Float16)(a * u1.x + b * v1.x);
        h[5] = (_Float16)(a * u1.y + b * v1.y);
        h[6] = (_Float16)(a * u1.z + b * v1.z);
        h[7] = (_Float16)(a * u1.w + b * v1.w);
        *(half8*)(wp + base) = h;
    }
}

// ---------------------------------------------------------------------------
// NT GEMM  out[n,o] = (sum_k Xq[n,k]*Wp[o,k]) * sx[n] + bias[o]
// 128x128 block tile, BK=32, 4 waves (2x2), each wave 64x64 via 4x4 grid of
// 16x16x32 f16 MFMA. global_load_lds width=16 staging with XOR bank swizzle:
//   LDS chunk c of row r holds global k-chunk (c ^ ((r>>1)&3))
// which spreads the 8-way bank aliasing of the 64B-stride fragment reads to
// 2-way (free). The DMA constraint (LDS addr == base + lane*16) still holds
// because only the *global* source column is swizzled per-lane.
// ---------------------------------------------------------------------------
__device__ inline void async_load16(const void* g, void* l)
{
    __builtin_amdgcn_global_load_lds(
        (const __attribute__((address_space(1))) void*)g,
        (__attribute__((address_space(3))) void*)l, 16, 0, 0);
}

__global__ __launch_bounds__(256) void gemm_kernel(
    const _Float16* __restrict__ A,   // [N, K]
    const _Float16* __restrict__ B,   // [M, K]
    const float* __restrict__ sx,     // [N]
    const float* __restrict__ bias,   // [M]
    float* __restrict__ out)          // [N, M]
{
    __shared__ __align__(16) _Float16 As[128 * 32];
    __shared__ __align__(16) _Float16 Bs[128 * 32];

    const int t    = threadIdx.x;
    const int wave = t >> 6;
    const int lane = t & 63;

    // ---- L2 super-tile swizzle: 8x8 blocks per super-tile ----
    // grid = 2048 linear; o-supers = 4, n-supers = 8 (32x64 logical grid)
    const int tile = blockIdx.x >> 6;
    const int loc  = blockIdx.x & 63;
    const int o0   = ((tile & 3) * 8 + (loc & 7)) * 128;
    const int n0   = ((tile >> 2) * 8 + (loc >> 3)) * 128;

    // staging: lane -> (row = lane>>2, LDS chunk = lane&3); global chunk XOR'd
    const int srow = lane >> 2;
    const int scl  = lane & 3;                    // LDS chunk (fixed: lane*16)
    const int scg  = scl ^ ((srow >> 1) & 3);     // global chunk fetched
    const int gcol = scg * 8;                     // halves
    const int lcol = scl * 8;                     // halves

    const int n_off = (wave >> 1) * 64;
    const int o_off = (wave & 1) * 64;

    // fragment addressing: want global chunk fg for row fr
    const int fr = lane & 15;
    const int fg = lane >> 4;
    const int fk = (fg ^ ((fr >> 1) & 3)) * 8;    // swizzled LDS chunk, halves

    f32x4 acc[4][4] = {};

    for (int kk = 0; kk < K_DIM; kk += 32) {
#pragma unroll
        for (int j = 0; j < 2; ++j) {
            const int row = j * 64 + wave * 16 + srow;
            async_load16(A + (size_t)(n0 + row) * K_DIM + kk + gcol,
                         &As[row * 32 + lcol]);
            async_load16(B + (size_t)(o0 + row) * K_DIM + kk + gcol,
                         &Bs[row * 32 + lcol]);
        }
        __syncthreads();

        half8 af[4], bf[4];
#pragma unroll
        for (int i = 0; i < 4; ++i)
            af[i] = *(const half8*)&As[(n_off + i * 16 + fr) * 32 + fk];
#pragma unroll
        for (int j = 0; j < 4; ++j)
            bf[j] = *(const half8*)&Bs[(o_off + j * 16 + fr) * 32 + fk];

#pragma unroll
        for (int i = 0; i < 4; ++i)
#pragma unroll
            for (int j = 0; j < 4; ++j)
                acc[i][j] = __builtin_amdgcn_mfma_f32_16x16x32_f16(
                    af[i], bf[j], acc[i][j], 0, 0, 0);

        __syncthreads();
    }

    // epilogue: C/D layout col = lane&15, row = (lane>>4)*4 + reg
#pragma unroll
    for (int i = 0; i < 4; ++i) {
        const int nbase = n0 + n_off + i * 16 + (lane >> 4) * 4;
#pragma unroll
        for (int r = 0; r < 4; ++r) {
            const float s = sx[nbase + r];
            float* orow = out + (size_t)(nbase + r) * M_DIM;
#pragma unroll
            for (int j = 0; j < 4; ++j) {
                const int o = o0 + o_off + j * 16 + (lane & 15);
                orow[o] = acc[i][j][r] * s + bias[o];
            }
        }
    }
}

// ---------------------------------------------------------------------------
extern "C" void kernel_launch(void* const* d_in, const int* in_sizes, int n_in,
                              void* d_out, int out_size, void* d_ws, size_t ws_size,
                              hipStream_t stream)
{
    const float* x    = (const float*)d_in[0];
    const float* w0   = (const float*)d_in[1];
    const float* w1   = (const float*)d_in[2];
    const float* s0   = (const float*)d_in[3];
    const float* s1   = (const float*)d_in[4];
    const float* bias = (const float*)d_in[5];
    float* out = (float*)d_out;

    char* ws = (char*)d_ws;
    _Float16* xq = (_Float16*)ws;                                   // 64 MiB
    _Float16* wp = (_Float16*)(ws + (size_t)N_ROWS * K_DIM * 2);    // 32 MiB
    float*    sx = (float*)(ws + (size_t)N_ROWS * K_DIM * 2
                               + (size_t)M_DIM * K_DIM * 2);        // 32 KiB

    prologue_kernel<<<N_ROWS + (M_DIM * K_DIM) / (256 * 8), 256, 0, stream>>>(
        x, xq, sx, w0, w1, s0, s1, wp);

    gemm_kernel<<<(N_ROWS / 128) * (M_DIM / 128), 256, 0, stream>>>(
        xq, wp, sx, bias, out);
}